// Round 12
// baseline (112.853 us; speedup 1.0000x reference)
//
#include <hip/hip_runtime.h>
#include <math.h>

// B=256, P=40, S=60, D=64. Zero-LDS register-resident chain.
// Round-12: dispatch-rate fix. Unified model of R2-R11: chip-wide wave
// dispatch ~100 waves/us; every non-spill round sat at it (10240 waves ->
// ~104-133 us). R11's body is good (124 VGPR, no spill, VALU-dieted) but
// 1 part/wave = 10240 waves = dispatch-bound. Now: 640 WGs x 256 thr =
// 2560 waves, each wave processes 4 consecutive parts in a ROLLED loop
// (#pragma unroll 1 -> liveness flat at ~124 VGPR; <=128 => 16 waves/CU).
// R8's multi-part failure was unroll+ping-pong liveness, not the concept.
//
// Register-chain trick: MFMA contraction is invariant to permuting the k-dim.
// C/D output holds the row-dim in-lane as {16mt+4g+j}; the next GEMM
// contracting that dim takes both operands by pure register reindexing:
//     frag[t][ks] = pk16( acc[2ks][t], acc[2ks+1][t] )
// map pi(ks,i,g)=16*(2ks+(i>>2))+4g+(i&3). W1/W2 pre-permuted to pi-layout.
//
// Layout facts (cdna4 guide, measured m89/m91):
//   C/D: lane holds col=lane&15, rows 16mt+4(lane>>4)+j
//   A/B: row(col)=lane&15, kappa = 32ks+8(lane>>4)+i

typedef _Float16 half8 __attribute__((ext_vector_type(8)));
typedef __fp16 fp16x2 __attribute__((ext_vector_type(2)));
typedef float f4 __attribute__((ext_vector_type(4)));

#define MFMA16(a, b, c) __builtin_amdgcn_mfma_f32_16x16x32_f16((a), (b), (c), 0, 0, 0)

__global__ __launch_bounds__(256) void prep_weights(
    const float* __restrict__ Wq, const float* __restrict__ Wk,
    const float* __restrict__ Wv, const float* __restrict__ W1,
    const float* __restrict__ W2, _Float16* __restrict__ wsH) {
    int idx = blockIdx.x * 256 + threadIdx.x;  // 0..20479
    int m = idx >> 12, r = idx & 4095;
    const float* src = (m == 0) ? Wq : (m == 1) ? Wk : (m == 2) ? Wv
                        : (m == 3) ? W1 : W2;
    float v;
    if (m < 3) {
        v = src[r];  // natural row-major [e][d]
    } else {
        // pi-permuted: position (e, kappa) holds W[e][ d=16*(2ks+(i>>2))+4g+(i&3) ]
        int e = r >> 6, kp = r & 63;
        int ks = kp >> 5, gg = (kp >> 3) & 3, i = kp & 7;
        int d = 16 * (2 * ks + (i >> 2)) + 4 * gg + (i & 3);
        v = src[e * 64 + d];
    }
    wsH[idx] = (_Float16)v;
}

// Packed f32x4 + f32x4 -> half8 via v_cvt_pkrtz_f16_f32 (4 insts total).
__device__ __forceinline__ half8 pk8(f4 a, f4 b) {
    union { half8 h; fp16x2 p[4]; } u;
    u.p[0] = __builtin_amdgcn_cvt_pkrtz(a[0], a[1]);
    u.p[1] = __builtin_amdgcn_cvt_pkrtz(a[2], a[3]);
    u.p[2] = __builtin_amdgcn_cvt_pkrtz(b[0], b[1]);
    u.p[3] = __builtin_amdgcn_cvt_pkrtz(b[2], b[3]);
    return u.h;
}

// Apply bias (+relu) to acc in place, then build pi-layout fragments.
// BIASMODE: 0 = row bias brow[mt][j] (feature 16mt+4g+j), 1 = col bias bcol[nt]
// (feature 16nt+lo), 2 = none.
template <int BIASMODE, bool RELU>
__device__ __forceinline__ void mk_frags(half8 fr[4][2], f4 acc[4][4],
                                         const f4* brow, const float* bcol) {
    #pragma unroll
    for (int mt = 0; mt < 4; ++mt)
        #pragma unroll
        for (int nt = 0; nt < 4; ++nt)
            #pragma unroll
            for (int j = 0; j < 4; ++j) {
                float v = acc[mt][nt][j];
                if (BIASMODE == 0) v += brow[mt][j];
                if (BIASMODE == 1) v += bcol[nt];
                if (RELU) v = fmaxf(v, 0.f);
                acc[mt][nt][j] = v;
            }
    #pragma unroll
    for (int t = 0; t < 4; ++t)
        #pragma unroll
        for (int ks = 0; ks < 2; ++ks)
            fr[t][ks] = pk8(acc[2 * ks][t], acc[2 * ks + 1][t]);
}

__device__ __forceinline__ void load_x(half8 xf[4][2], const float* __restrict__ xp,
                                       int lo, int g) {
    #pragma unroll
    for (int t = 0; t < 4; ++t) {
        int r = 16 * t + lo;
        #pragma unroll
        for (int ks = 0; ks < 2; ++ks) {
            if (r < 60) {
                const float* p = xp + r * 64 + ks * 32 + g * 8;
                xf[t][ks] = pk8(*(const f4*)p, *(const f4*)(p + 4));
            } else {
                half8 z = {};
                xf[t][ks] = z;
            }
        }
    }
}

// First K-step uses the constant zero quad as C (no acc zero-init needed).
// AEXPR/BEXPR use variables t, ks.
#define GEMM(AEXPR, BEXPR)                                                   \
    do {                                                                     \
        _Pragma("unroll")                                                    \
        for (int ks = 0; ks < 2; ++ks) {                                     \
            half8 afr[4], bfr[4];                                            \
            _Pragma("unroll")                                                \
            for (int t = 0; t < 4; ++t) { afr[t] = (AEXPR); bfr[t] = (BEXPR); } \
            _Pragma("unroll")                                                \
            for (int mt = 0; mt < 4; ++mt)                                   \
                _Pragma("unroll")                                            \
                for (int nt = 0; nt < 4; ++nt)                               \
                    acc[mt][nt] = MFMA16(afr[mt], bfr[nt],                   \
                                         ks == 0 ? zc : acc[mt][nt]);        \
        }                                                                    \
    } while (0)

#define WFR(widx) (*(const half8*)&wH[(widx) * 4096 + (16 * t + lo) * 64 + 32 * ks + 8 * g])

__global__ __launch_bounds__(256, 1) void fused_f16(
    const float* __restrict__ x, const _Float16* __restrict__ wH,
    const float* __restrict__ bq, const float* __restrict__ bk,
    const float* __restrict__ bv, const float* __restrict__ b1,
    const float* __restrict__ b2, const float* __restrict__ W3,
    const float* __restrict__ b3, float* __restrict__ out) {
    const int l = threadIdx.x & 63;   // lane
    const int w = threadIdx.x >> 6;   // wave 0..3 (independent part streams)
    const int lo = l & 15, g = l >> 4;
    const int part0 = blockIdx.x * 16 + w * 4;  // 4 consecutive parts per wave

    const f4 zc = {0.f, 0.f, 0.f, 0.f};

    #pragma unroll 1   // ROLLED: keep liveness flat (R8 lesson)
    for (int it = 0; it < 4; ++it) {
        const int part = part0 + it;
        const float* __restrict__ xp = x + (size_t)part * (60 * 64);

        f4 acc[4][4];
        f4 brow[4];
        half8 xf[4][2], wf[4][2], qf[4][2], kf[4][2], vf[4][2], pf[4][2],
              wtf[4][2], h1f[4][2];

        load_x(xf, xp, lo, g);

        // ---- qT = Wq * xT : lane holds q[s=16nt+lo][e=16mt+4g+j]
        #pragma unroll
        for (int t = 0; t < 4; ++t)
            #pragma unroll
            for (int ks = 0; ks < 2; ++ks) wf[t][ks] = WFR(0);
        GEMM(wf[t][ks], xf[t][ks]);
        #pragma unroll
        for (int mt = 0; mt < 4; ++mt) brow[mt] = *(const f4*)&bq[16 * mt + 4 * g];
        mk_frags<0, false>(qf, acc, brow, nullptr);

        // ---- kT = Wk * xT : lane holds k[c=16nt+lo][d=16mt+4g+j]
        #pragma unroll
        for (int t = 0; t < 4; ++t)
            #pragma unroll
            for (int ks = 0; ks < 2; ++ks) wf[t][ks] = WFR(1);
        GEMM(wf[t][ks], xf[t][ks]);
        #pragma unroll
        for (int mt = 0; mt < 4; ++mt) brow[mt] = *(const f4*)&bk[16 * mt + 4 * g];
        mk_frags<0, false>(kf, acc, brow, nullptr);

        // ---- scoresT[c][s] = sum_d k[c][d] q[s][d]  (d in-lane on both).
        // Ordered before the v projection to cap peak liveness.
        GEMM(kf[t][ks], qf[t][ks]);

        // ---- softmax over c, scale 1/8, NO max-subtraction: scores ~N(0,1),
        // |s|<~7 over the whole tensor -> exp safe in f32. Mask c>=60 to 0.
        #pragma unroll
        for (int nt = 0; nt < 4; ++nt) {
            float sum = 0.f;
            #pragma unroll
            for (int mt = 0; mt < 4; ++mt)
                #pragma unroll
                for (int j = 0; j < 4; ++j) {
                    float e = (mt == 3 && g == 3)
                                  ? 0.f
                                  : exp2f(acc[mt][nt][j] * 0.1803368801111137f);
                    acc[mt][nt][j] = e;
                    sum += e;
                }
            sum += __shfl_xor(sum, 16);
            sum += __shfl_xor(sum, 32);
            float inv = 1.f / sum;
            #pragma unroll
            for (int mt = 0; mt < 4; ++mt)
                #pragma unroll
                for (int j = 0; j < 4; ++j) acc[mt][nt][j] *= inv;
        }
        mk_frags<2, false>(pf, acc, nullptr, nullptr);

        // ---- v = x * WvT : lane holds v[s=16mt+4g+j][d=16nt+lo]  (xf dies here)
        #pragma unroll
        for (int t = 0; t < 4; ++t)
            #pragma unroll
            for (int ks = 0; ks < 2; ++ks) wf[t][ks] = WFR(2);
        GEMM(xf[t][ks], wf[t][ks]);
        {
            float bcol[4];
            #pragma unroll
            for (int nt = 0; nt < 4; ++nt) bcol[nt] = bv[16 * nt + lo];
            mk_frags<1, false>(vf, acc, nullptr, bcol);
        }

        // ---- weightedT[d][s] = sum_c vT[d][c] P[s][c]  (c in-lane on both)
        GEMM(vf[t][ks], pf[t][ks]);
        mk_frags<2, false>(wtf, acc, nullptr, nullptr);

        // ---- h1T = W1 * weightedT, relu+b1  (W1 pi-permuted)
        #pragma unroll
        for (int t = 0; t < 4; ++t)
            #pragma unroll
            for (int ks = 0; ks < 2; ++ks) wf[t][ks] = WFR(3);
        GEMM(wf[t][ks], wtf[t][ks]);
        #pragma unroll
        for (int mt = 0; mt < 4; ++mt) brow[mt] = *(const f4*)&b1[16 * mt + 4 * g];
        mk_frags<0, true>(h1f, acc, brow, nullptr);

        // ---- h2T = W2 * h1T, relu+b2 (keep f32 in acc)
        #pragma unroll
        for (int t = 0; t < 4; ++t)
            #pragma unroll
            for (int ks = 0; ks < 2; ++ks) wf[t][ks] = WFR(4);
        GEMM(wf[t][ks], h1f[t][ks]);
        #pragma unroll
        for (int mt = 0; mt < 4; ++mt) brow[mt] = *(const f4*)&b2[16 * mt + 4 * g];
        #pragma unroll
        for (int mt = 0; mt < 4; ++mt)
            #pragma unroll
            for (int nt = 0; nt < 4; ++nt)
                #pragma unroll
                for (int j = 0; j < 4; ++j)
                    acc[mt][nt][j] = fmaxf(acc[mt][nt][j] + brow[mt][j], 0.f);

        // ---- out[s] = sum_e h2T[e][s] * W3[e] + b3
        f4 w3r[4];
        #pragma unroll
        for (int mt = 0; mt < 4; ++mt) w3r[mt] = *(const f4*)&W3[16 * mt + 4 * g];
        float b3v = b3[0];
        #pragma unroll
        for (int nt = 0; nt < 4; ++nt) {
            float sres = 0.f;
            #pragma unroll
            for (int mt = 0; mt < 4; ++mt)
                #pragma unroll
                for (int j = 0; j < 4; ++j) sres += acc[mt][nt][j] * w3r[mt][j];
            sres += __shfl_xor(sres, 16);
            sres += __shfl_xor(sres, 32);
            if (g == 0) {
                int s = 16 * nt + lo;
                if (s < 60) out[(size_t)part * 60 + s] = sres + b3v;
            }
        }
    }
}

extern "C" void kernel_launch(void* const* d_in, const int* in_sizes, int n_in,
                              void* d_out, int out_size, void* d_ws, size_t ws_size,
                              hipStream_t stream) {
    const float* x  = (const float*)d_in[0];
    const float* Wq = (const float*)d_in[1];
    const float* bq = (const float*)d_in[2];
    const float* Wk = (const float*)d_in[3];
    const float* bk = (const float*)d_in[4];
    const float* Wv = (const float*)d_in[5];
    const float* bv = (const float*)d_in[6];
    const float* W1 = (const float*)d_in[7];
    const float* b1 = (const float*)d_in[8];
    const float* W2 = (const float*)d_in[9];
    const float* b2 = (const float*)d_in[10];
    const float* W3 = (const float*)d_in[11];
    const float* b3 = (const float*)d_in[12];
    _Float16* wsH = (_Float16*)d_ws;  // 5 * 4096 halves = 40 KB

    prep_weights<<<80, 256, 0, stream>>>(Wq, Wk, Wv, W1, W2, wsH);
    // 640 WGs x 256 thr = 2560 waves; each wave handles 4 consecutive parts
    // (rolled loop). Dispatch floor ~26 us at ~100 waves/us.
    fused_f16<<<640, 256, 0, stream>>>(x, wsH, bq, bk, bv, b1, b2, W3, b3,
                                       (float*)d_out);
}

// Round 13
// 87.050 us; speedup vs baseline: 1.2964x; 1.2964x over previous
//
#include <hip/hip_runtime.h>
#include <math.h>

// B=256, P=40, S=60, D=64. Register-resident MFMA chain, weights in LDS.
// Round-13: R12 showed a rolled multi-part loop hoists 64-bit global weight
// address chains + pipelines loads -> VGPR 240 -> ~2 waves/CU -> latency-bound.
// Fix: (1) weights coop-loaded to LDS once per WG (40 KB, XOR-swizzled for
// conflict-free ds_read_b128 fragments); in-loop weight access is 32-bit LDS,
// ~120cyc. (2) bias folded into the MFMA C operand of the first K-step
// (C != D) -> deletes ~320 VALU bias adds/part. (3) 640 WGs x 256 thr,
// 4 parts/wave rolled loop = 2560 waves (wave-rate floor ~26 us).
//
// Register-chain trick: MFMA contraction is invariant to permuting the k-dim.
// C/D output holds the row-dim in-lane as {16mt+4g+j}; the next GEMM
// contracting that dim takes both operands by pure register reindexing:
//     frag[t][ks] = pk16( acc[2ks][t], acc[2ks+1][t] )
// map pi(ks,i,g)=16*(2ks+(i>>2))+4g+(i&3). W1/W2 pre-permuted to pi-layout.
//
// Layout facts (cdna4 guide, measured m89/m91):
//   C/D: lane holds col=lane&15, rows 16mt+4(lane>>4)+j
//   A/B: row(col)=lane&15, kappa = 32ks+8(lane>>4)+i

typedef _Float16 half8 __attribute__((ext_vector_type(8)));
typedef __fp16 fp16x2 __attribute__((ext_vector_type(2)));
typedef float f4 __attribute__((ext_vector_type(4)));

#define MFMA16(a, b, c) __builtin_amdgcn_mfma_f32_16x16x32_f16((a), (b), (c), 0, 0, 0)

__global__ __launch_bounds__(256) void prep_weights(
    const float* __restrict__ Wq, const float* __restrict__ Wk,
    const float* __restrict__ Wv, const float* __restrict__ W1,
    const float* __restrict__ W2, _Float16* __restrict__ wsH) {
    int idx = blockIdx.x * 256 + threadIdx.x;  // 0..20479
    int m = idx >> 12, r = idx & 4095;
    const float* src = (m == 0) ? Wq : (m == 1) ? Wk : (m == 2) ? Wv
                        : (m == 3) ? W1 : W2;
    float v;
    if (m < 3) {
        v = src[r];  // natural row-major [e][d]
    } else {
        // pi-permuted: position (e, kappa) holds W[e][ d=16*(2ks+(i>>2))+4g+(i&3) ]
        int e = r >> 6, kp = r & 63;
        int ks = kp >> 5, gg = (kp >> 3) & 3, i = kp & 7;
        int d = 16 * (2 * ks + (i >> 2)) + 4 * gg + (i & 3);
        v = src[e * 64 + d];
    }
    wsH[idx] = (_Float16)v;
}

// Packed f32x4 + f32x4 -> half8 via v_cvt_pkrtz_f16_f32 (4 insts).
__device__ __forceinline__ half8 pk8(f4 a, f4 b) {
    union { half8 h; fp16x2 p[4]; } u;
    u.p[0] = __builtin_amdgcn_cvt_pkrtz(a[0], a[1]);
    u.p[1] = __builtin_amdgcn_cvt_pkrtz(a[2], a[3]);
    u.p[2] = __builtin_amdgcn_cvt_pkrtz(b[0], b[1]);
    u.p[3] = __builtin_amdgcn_cvt_pkrtz(b[2], b[3]);
    return u.h;
}

// acc -> pi-layout fragments (optional relu; bias already folded via C-in).
template <bool RELU>
__device__ __forceinline__ void mk_frags(half8 fr[4][2], f4 acc[4][4]) {
    #pragma unroll
    for (int t = 0; t < 4; ++t)
        #pragma unroll
        for (int ks = 0; ks < 2; ++ks) {
            f4 a = acc[2 * ks][t], b = acc[2 * ks + 1][t];
            if (RELU) {
                #pragma unroll
                for (int j = 0; j < 4; ++j) {
                    a[j] = fmaxf(a[j], 0.f);
                    b[j] = fmaxf(b[j], 0.f);
                }
            }
            fr[t][ks] = pk8(a, b);
        }
}

__device__ __forceinline__ void load_x(half8 xf[4][2], const float* __restrict__ xp,
                                       int lo, int g) {
    #pragma unroll
    for (int t = 0; t < 4; ++t) {
        int r = 16 * t + lo;
        #pragma unroll
        for (int ks = 0; ks < 2; ++ks) {
            if (r < 60) {
                const float* p = xp + r * 64 + ks * 32 + g * 8;
                xf[t][ks] = pk8(*(const f4*)p, *(const f4*)(p + 4));
            } else {
                half8 z = {};
                xf[t][ks] = z;
            }
        }
    }
}

// CEXPR is the C operand of the FIRST K-step (bias quad or zc); uses mt, nt.
#define GEMM(AEXPR, BEXPR, CEXPR)                                            \
    do {                                                                     \
        _Pragma("unroll")                                                    \
        for (int ks = 0; ks < 2; ++ks) {                                     \
            half8 afr[4], bfr[4];                                            \
            _Pragma("unroll")                                                \
            for (int t = 0; t < 4; ++t) { afr[t] = (AEXPR); bfr[t] = (BEXPR); } \
            _Pragma("unroll")                                                \
            for (int mt = 0; mt < 4; ++mt)                                   \
                _Pragma("unroll")                                            \
                for (int nt = 0; nt < 4; ++nt)                               \
                    acc[mt][nt] = MFMA16(afr[mt], bfr[nt],                   \
                                         ks == 0 ? (CEXPR) : acc[mt][nt]);   \
        }                                                                    \
    } while (0)

// LDS weight fragment read: element (row=16t+lo, kappa=32ks+8g) of matrix widx,
// 16B chunk XOR-swizzled by (lo&7)<<3 halves (row&7 == lo&7 since 16t%8==0).
#define LFR(widx) (*(const half8*)&wlds[(widx) * 4096 + (16 * t + lo) * 64 + \
                                        ((32 * ks + 8 * g) ^ ((lo & 7) << 3))])

__global__ __launch_bounds__(256, 1) void fused_f16(
    const float* __restrict__ x, const _Float16* __restrict__ wH,
    const float* __restrict__ bq, const float* __restrict__ bk,
    const float* __restrict__ bv, const float* __restrict__ b1,
    const float* __restrict__ b2, const float* __restrict__ W3,
    const float* __restrict__ b3, float* __restrict__ out) {
    __shared__ __align__(16) _Float16 wlds[5 * 4096];  // 40 KB

    const int tid = threadIdx.x;
    const int l = tid & 63;           // lane
    const int w = tid >> 6;           // wave 0..3
    const int lo = l & 15, g = l >> 4;

    // ---- cooperative weight load global->LDS with write-side swizzle:
    // dst halfidx = widx*4096 + row*64 + ((c*8) ^ ((row&7)<<3)), c = 16B chunk.
    #pragma unroll
    for (int rep = 0; rep < 10; ++rep) {
        int chunk = rep * 256 + tid;          // 0..2559
        int widx = chunk >> 9;
        int rem = chunk & 511;
        int row = rem >> 3, c = rem & 7;
        *(half8*)&wlds[widx * 4096 + row * 64 + ((c * 8) ^ ((row & 7) << 3))] =
            *(const half8*)&wH[widx * 4096 + row * 64 + c * 8];
    }
    __syncthreads();  // only barrier; waves independent afterwards

    const int part0 = blockIdx.x * 16 + w * 4;
    const f4 zc = {0.f, 0.f, 0.f, 0.f};

    #pragma unroll 1
    for (int it = 0; it < 4; ++it) {
        const int part = part0 + it;
        const float* __restrict__ xp = x + (size_t)part * (60 * 64);

        f4 acc[4][4];
        f4 brow[4];
        half8 xf[4][2], qf[4][2], kf[4][2], vf[4][2], pf[4][2], wtf[4][2],
              h1f[4][2];

        load_x(xf, xp, lo, g);

        // ---- qT = Wq * xT + bq (bias via C-in; rows of D are features)
        #pragma unroll
        for (int mt = 0; mt < 4; ++mt) brow[mt] = *(const f4*)&bq[16 * mt + 4 * g];
        GEMM(LFR(0), xf[t][ks], brow[mt]);
        mk_frags<false>(qf, acc);

        // ---- kT = Wk * xT + bk
        #pragma unroll
        for (int mt = 0; mt < 4; ++mt) brow[mt] = *(const f4*)&bk[16 * mt + 4 * g];
        GEMM(LFR(1), xf[t][ks], brow[mt]);
        mk_frags<false>(kf, acc);

        // ---- scoresT[c][s] = sum_d k[c][d] q[s][d]
        GEMM(kf[t][ks], qf[t][ks], zc);

        // ---- softmax over c, scale 1/8 folded into exp2; no max-sub
        // (scores ~N(0,1), 6-sigma bounded). Mask c>=60 to 0.
        #pragma unroll
        for (int nt = 0; nt < 4; ++nt) {
            float sum = 0.f;
            #pragma unroll
            for (int mt = 0; mt < 4; ++mt)
                #pragma unroll
                for (int j = 0; j < 4; ++j) {
                    float e = (mt == 3 && g == 3)
                                  ? 0.f
                                  : exp2f(acc[mt][nt][j] * 0.1803368801111137f);
                    acc[mt][nt][j] = e;
                    sum += e;
                }
            sum += __shfl_xor(sum, 16);
            sum += __shfl_xor(sum, 32);
            float inv = 1.f / sum;
            #pragma unroll
            for (int mt = 0; mt < 4; ++mt)
                #pragma unroll
                for (int j = 0; j < 4; ++j) acc[mt][nt][j] *= inv;
        }
        mk_frags<false>(pf, acc);

        // ---- v = x * WvT + bv (cols of D are features -> col-splat C-in)
        {
            float bcol[4];
            #pragma unroll
            for (int nt = 0; nt < 4; ++nt) bcol[nt] = bv[16 * nt + lo];
            GEMM(xf[t][ks], LFR(2),
                 ((f4){bcol[nt], bcol[nt], bcol[nt], bcol[nt]}));
        }
        mk_frags<false>(vf, acc);

        // ---- weightedT[d][s] = sum_c vT[d][c] P[s][c]
        GEMM(vf[t][ks], pf[t][ks], zc);
        mk_frags<false>(wtf, acc);

        // ---- h1T = relu(W1 * weightedT + b1)   (W1 pi-permuted)
        #pragma unroll
        for (int mt = 0; mt < 4; ++mt) brow[mt] = *(const f4*)&b1[16 * mt + 4 * g];
        GEMM(LFR(3), wtf[t][ks], brow[mt]);
        mk_frags<true>(h1f, acc);

        // ---- h2T = relu(W2 * h1T + b2) kept f32 in acc
        #pragma unroll
        for (int mt = 0; mt < 4; ++mt) brow[mt] = *(const f4*)&b2[16 * mt + 4 * g];
        GEMM(LFR(4), h1f[t][ks], brow[mt]);
        #pragma unroll
        for (int mt = 0; mt < 4; ++mt)
            #pragma unroll
            for (int nt = 0; nt < 4; ++nt)
                #pragma unroll
                for (int j = 0; j < 4; ++j)
                    acc[mt][nt][j] = fmaxf(acc[mt][nt][j], 0.f);

        // ---- out[s] = sum_e h2T[e][s] * W3[e] + b3
        f4 w3r[4];
        #pragma unroll
        for (int mt = 0; mt < 4; ++mt) w3r[mt] = *(const f4*)&W3[16 * mt + 4 * g];
        float b3v = b3[0];
        #pragma unroll
        for (int nt = 0; nt < 4; ++nt) {
            float sres = 0.f;
            #pragma unroll
            for (int mt = 0; mt < 4; ++mt)
                #pragma unroll
                for (int j = 0; j < 4; ++j) sres += acc[mt][nt][j] * w3r[mt][j];
            sres += __shfl_xor(sres, 16);
            sres += __shfl_xor(sres, 32);
            if (g == 0) {
                int s = 16 * nt + lo;
                if (s < 60) out[(size_t)part * 60 + s] = sres + b3v;
            }
        }
    }
}

extern "C" void kernel_launch(void* const* d_in, const int* in_sizes, int n_in,
                              void* d_out, int out_size, void* d_ws, size_t ws_size,
                              hipStream_t stream) {
    const float* x  = (const float*)d_in[0];
    const float* Wq = (const float*)d_in[1];
    const float* bq = (const float*)d_in[2];
    const float* Wk = (const float*)d_in[3];
    const float* bk = (const float*)d_in[4];
    const float* Wv = (const float*)d_in[5];
    const float* bv = (const float*)d_in[6];
    const float* W1 = (const float*)d_in[7];
    const float* b1 = (const float*)d_in[8];
    const float* W2 = (const float*)d_in[9];
    const float* b2 = (const float*)d_in[10];
    const float* W3 = (const float*)d_in[11];
    const float* b3 = (const float*)d_in[12];
    _Float16* wsH = (_Float16*)d_ws;  // 5 * 4096 halves = 40 KB

    prep_weights<<<80, 256, 0, stream>>>(Wq, Wk, Wv, W1, W2, wsH);
    // 640 WGs x 256 thr = 2560 waves; 4 parts/wave (rolled), weights in LDS.
    fused_f16<<<640, 256, 0, stream>>>(x, wsH, bq, bk, bv, b1, b2, W3, b3,
                                       (float*)d_out);
}